// Round 2
// baseline (1621.493 us; speedup 1.0000x reference)
//
#include <hip/hip_runtime.h>
#include <math.h>

#define D_    1024
#define H_    16
#define E_    64
#define DF_   4096
#define NL_   3
#define V_    32000
#define B_    2
#define LSEQ_ 2048
#define M_    (B_*LSEQ_)     // 4096 rows
#define QKVW  (3*D_)         // 3072

typedef __attribute__((ext_vector_type(8))) short bf16x8;   // 8 bf16 = 4 VGPR (MFMA operand)
typedef __attribute__((ext_vector_type(4))) float f32x4;
typedef __attribute__((ext_vector_type(4))) unsigned short us4_t;

__device__ __forceinline__ float bfr2f(unsigned short u){ return __uint_as_float(((unsigned)u)<<16); }
__device__ __forceinline__ unsigned short f2bfr(float f){
  unsigned u = __float_as_uint(f);
  u += 0x7fffu + ((u>>16)&1u);          // RNE
  return (unsigned short)(u>>16);
}
__device__ __forceinline__ void gl_lds16(const unsigned short* g, unsigned short* l){
  __builtin_amdgcn_global_load_lds((const __attribute__((address_space(1))) void*)g,
                                   (__attribute__((address_space(3))) void*)l, 16, 0, 0);
}

// ---------------- embedding: x_f32[r][c] = tok_emb[tok[r]][c] + pos_emb[l][c] ----------------
__global__ __launch_bounds__(256) void embed_kernel(const int* __restrict__ tokens,
                                                    const float* __restrict__ tok_emb,
                                                    const float* __restrict__ pos_emb,
                                                    float* __restrict__ x){
  const int r = blockIdx.x, tid = threadIdx.x;
  const int l = r & (LSEQ_-1);
  const int t = tokens[r];
  float4 te = ((const float4*)(tok_emb + (size_t)t*D_))[tid];
  float4 pe = ((const float4*)(pos_emb + (size_t)l*D_))[tid];
  float4 o = {te.x+pe.x, te.y+pe.y, te.z+pe.z, te.w+pe.w};
  ((float4*)(x + (size_t)r*D_))[tid] = o;
}

// ---------------- layernorm: h_bf16[r][c] = LN(x[r])*g + b ----------------
__global__ __launch_bounds__(256) void ln_kernel(const float* __restrict__ x,
                                                 const float* __restrict__ g,
                                                 const float* __restrict__ b,
                                                 unsigned short* __restrict__ h){
  const int r = blockIdx.x, tid = threadIdx.x;
  const int wave = tid>>6, lane = tid&63;
  float4 v = ((const float4*)(x + (size_t)r*D_))[tid];
  float s  = v.x+v.y+v.z+v.w;
  float s2 = v.x*v.x+v.y*v.y+v.z*v.z+v.w*v.w;
  #pragma unroll
  for (int off=1; off<64; off<<=1){ s += __shfl_xor(s,off); s2 += __shfl_xor(s2,off); }
  __shared__ float red[8];
  if (!lane){ red[wave]=s; red[4+wave]=s2; }
  __syncthreads();
  s  = red[0]+red[1]+red[2]+red[3];
  s2 = red[4]+red[5]+red[6]+red[7];
  const float mean = s*(1.f/D_);
  const float var  = s2*(1.f/D_) - mean*mean;
  const float rstd = rsqrtf(var + 1e-5f);
  const int c0 = tid*4;
  float4 gg = ((const float4*)g)[tid];
  float4 bb = ((const float4*)b)[tid];
  us4_t ov;
  ov[0] = f2bfr((v.x-mean)*rstd*gg.x + bb.x);
  ov[1] = f2bfr((v.y-mean)*rstd*gg.y + bb.y);
  ov[2] = f2bfr((v.z-mean)*rstd*gg.z + bb.z);
  ov[3] = f2bfr((v.w-mean)*rstd*gg.w + bb.w);
  *(us4_t*)&h[(size_t)r*D_ + c0] = ov;
}

// ---------------- transpose+cast: W_f32[K][N] -> WT_bf16[(rowOff+n)][k] (stride K) -------------
__global__ __launch_bounds__(256) void transpose_kernel(const float* __restrict__ W,
                                                        unsigned short* __restrict__ WT,
                                                        int N, int K, int rowOff){
  __shared__ unsigned short T[64*65];
  const int n0 = blockIdx.x*64, k0 = blockIdx.y*64;
  const int tid = threadIdx.x;
  const int kr = tid>>2, nc = (tid&3)*16;
  const float* src = W + (size_t)(k0+kr)*N + n0 + nc;
  #pragma unroll
  for (int j0=0;j0<16;j0+=4){
    float4 f = *(const float4*)(src + j0);
    T[(nc+j0+0)*65 + kr] = f2bfr(f.x);
    T[(nc+j0+1)*65 + kr] = f2bfr(f.y);
    T[(nc+j0+2)*65 + kr] = f2bfr(f.z);
    T[(nc+j0+3)*65 + kr] = f2bfr(f.w);
  }
  __syncthreads();
  const int nr = tid>>2, kc = (tid&3)*16;
  bf16x8 o0, o1;
  #pragma unroll
  for (int j=0;j<8;j++){ o0[j] = (short)T[nr*65 + kc + j];
                         o1[j] = (short)T[nr*65 + kc + 8 + j]; }
  *(bf16x8*)&WT[(size_t)(rowOff+n0+nr)*K + k0 + kc]     = o0;
  *(bf16x8*)&WT[(size_t)(rowOff+n0+nr)*K + k0 + kc + 8] = o1;
}

__global__ void concat_bias(const float* __restrict__ a,
                            const float* __restrict__ b,
                            const float* __restrict__ c,
                            float* __restrict__ d){
  int i = blockIdx.x*256 + threadIdx.x;
  d[i] = (i < D_) ? a[i] : (i < 2*D_) ? b[i-D_] : c[i-2*D_];
}

// ---------------- GEMM: C[M][N] = A[M][K] * Bt[N][K]^T  (+bias, epilogue variants) -------------
// EPI 0: bf16 store ; 1: bf16 gelu store ; 2: resid_f32 += v ; 3: f32 store
template<int EPI>
__global__ __launch_bounds__(256) void gemm_bt(const unsigned short* __restrict__ A,
                                               const unsigned short* __restrict__ Bt,
                                               const float* __restrict__ bias,
                                               unsigned short* __restrict__ Cb,
                                               float* __restrict__ Cf,
                                               int K, int ldc){
  __shared__ unsigned short As[128*32];
  __shared__ unsigned short Bs[128*32];
  const int tid = threadIdx.x;
  const int wave = tid>>6, lane = tid&63;
  const int m0 = blockIdx.x*128, n0 = blockIdx.y*128;
  const int wr = wave>>1, wc = wave&1;
  const unsigned short* Ab = A + (size_t)m0*K;
  const unsigned short* Bb = Bt + (size_t)n0*K;
  f32x4 acc[4][4] = {};
  const int c1 = wave*64 + lane, r1 = c1>>2, k1 = (c1&3)*8;
  const int c2 = c1 + 256,       r2 = c2>>2, k2 = (c2&3)*8;
  for (int kt=0; kt<K; kt+=32){
    __syncthreads();
    gl_lds16(Ab + (size_t)r1*K + kt + k1, As + wave*512);
    gl_lds16(Ab + (size_t)r2*K + kt + k2, As + (wave+4)*512);
    gl_lds16(Bb + (size_t)r1*K + kt + k1, Bs + wave*512);
    gl_lds16(Bb + (size_t)r2*K + kt + k2, Bs + (wave+4)*512);
    __syncthreads();
    const int kq = (lane>>4)*8;
    bf16x8 af[4], bfv[4];
    #pragma unroll
    for (int mi=0;mi<4;mi++){
      int row = wr*64 + mi*16 + (lane&15);
      af[mi] = *(const bf16x8*)&As[row*32 + kq];
    }
    #pragma unroll
    for (int ni=0;ni<4;ni++){
      int row = wc*64 + ni*16 + (lane&15);
      bfv[ni] = *(const bf16x8*)&Bs[row*32 + kq];
    }
    #pragma unroll
    for (int mi=0;mi<4;mi++)
      #pragma unroll
      for (int ni=0;ni<4;ni++)
        acc[mi][ni] = __builtin_amdgcn_mfma_f32_16x16x32_bf16(af[mi], bfv[ni], acc[mi][ni], 0,0,0);
  }
  const int rq = (lane>>4)*4, cq = lane&15;
  #pragma unroll
  for (int mi=0;mi<4;mi++){
    #pragma unroll
    for (int ni=0;ni<4;ni++){
      #pragma unroll
      for (int j=0;j<4;j++){
        int r = m0 + wr*64 + mi*16 + rq + j;
        int c = n0 + wc*64 + ni*16 + cq;
        float v = acc[mi][ni][j] + bias[c];
        if (EPI==0)      Cb[(size_t)r*ldc + c] = f2bfr(v);
        else if (EPI==1) Cb[(size_t)r*ldc + c] = f2bfr(0.5f*v*(1.f+erff(v*0.70710678f)));
        else if (EPI==2) Cf[(size_t)r*D_ + c] += v;
        else             Cf[(size_t)r*ldc + c] = v;
      }
    }
  }
}

// ---------------- flash attention: qkv_bf16[M][3072] -> o_bf16[M][1024] ----------------
__global__ __launch_bounds__(256) void attn_kernel(const unsigned short* __restrict__ qkv,
                                                   unsigned short* __restrict__ o){
  const int qt = blockIdx.x, bh = blockIdx.y;
  const int b = bh>>4, h = bh&15;
  const int tid = threadIdx.x, wave = tid>>6, lane = tid&63;
  const int ql0 = qt*64;
  __shared__ unsigned short Qs[64*64];   // [q][e], 16B-chunk XOR swizzled
  __shared__ unsigned short Ks[64*64];   // [s][e], swizzled
  __shared__ unsigned short Vt[64*72];   // [e][s], padded
  __shared__ unsigned short Ps[64*72];   // [q][s], padded (per-wave private rows)
  const size_t base = (size_t)b*LSEQ_*QKVW + (size_t)h*E_;
  const unsigned short* qb = qkv + base;
  const unsigned short* kb = qkv + base + D_;
  const unsigned short* vb = qkv + base + 2*D_;
  // stage Q (inverse-swizzled global source, linear LDS dest)
  #pragma unroll
  for (int ii=0; ii<2; ii++){
    int i = wave + ii*4;
    int chunk = i*64 + lane, r = chunk>>3, cc = chunk&7;
    gl_lds16(qb + (size_t)(ql0 + r)*QKVW + ((cc^(r&7))*8), Qs + i*512);
  }
  float m4[4] = {-3e38f,-3e38f,-3e38f,-3e38f};
  float l4[4] = {0.f,0.f,0.f,0.f};
  f32x4 oacc[4] = {};
  const int nkv = qt + 1;
  for (int t=0; t<nkv; t++){
    const int s0 = t*64;
    __syncthreads();                       // prior tile's reads done
    #pragma unroll
    for (int ii=0; ii<2; ii++){
      int i = wave + ii*4;
      int chunk = i*64 + lane, r = chunk>>3, cc = chunk&7;
      gl_lds16(kb + (size_t)(s0 + r)*QKVW + ((cc^(r&7))*8), Ks + i*512);
    }
    #pragma unroll
    for (int p=0;p<2;p++){                 // V transposed: lane = s
      int e0 = wave*8 + p*32;
      bf16x8 vv = *(const bf16x8*)(vb + (size_t)(s0 + lane)*QKVW + e0);
      #pragma unroll
      for (int j=0;j<8;j++) Vt[(e0+j)*72 + lane] = (unsigned short)vv[j];
    }
    __syncthreads();                       // drains vmcnt + lgkm
    // S = Q K^T  (wave owns q-rows [wave*16, wave*16+16))
    f32x4 sacc[4] = {};
    #pragma unroll
    for (int ks=0; ks<2; ks++){
      int qrow = wave*16 + (lane&15);
      int qc = ks*4 + (lane>>4);
      bf16x8 a = *(const bf16x8*)&Qs[qrow*64 + ((qc^(qrow&7))*8)];
      #pragma unroll
      for (int fc=0; fc<4; fc++){
        int krow = fc*16 + (lane&15);
        bf16x8 bv = *(const bf16x8*)&Ks[krow*64 + ((qc^(krow&7))*8)];
        sacc[fc] = __builtin_amdgcn_mfma_f32_16x16x32_bf16(a, bv, sacc[fc], 0,0,0);
      }
    }
    // online softmax (rows of a lane: wave*16 + (lane>>4)*4 + j)
    float rm[4], al[4], rs[4];
    #pragma unroll
    for (int j=0;j<4;j++){
      int rowa = ql0 + wave*16 + (lane>>4)*4 + j;
      float mx = -3e38f;
      #pragma unroll
      for (int fc=0;fc<4;fc++){
        int cola = s0 + fc*16 + (lane&15);
        float sv = sacc[fc][j]*0.125f;
        if (cola > rowa) sv = -3e38f;      // causal mask
        sacc[fc][j] = sv;
        mx = fmaxf(mx, sv);
      }
      rm[j] = mx;
    }
    #pragma unroll
    for (int off=1; off<16; off<<=1)
      #pragma unroll
      for (int j=0;j<4;j++) rm[j] = fmaxf(rm[j], __shfl_xor(rm[j], off));
    #pragma unroll
    for (int j=0;j<4;j++){
      float mn = fmaxf(m4[j], rm[j]);
      al[j] = __expf(m4[j] - mn);
      m4[j] = mn; rs[j] = 0.f;
    }
    #pragma unroll
    for (int fc=0;fc<4;fc++)
      #pragma unroll
      for (int j=0;j<4;j++){
        float pv = __expf(sacc[fc][j] - m4[j]);
        sacc[fc][j] = pv; rs[j] += pv;
      }
    #pragma unroll
    for (int off=1; off<16; off<<=1)
      #pragma unroll
      for (int j=0;j<4;j++) rs[j] += __shfl_xor(rs[j], off);
    #pragma unroll
    for (int j=0;j<4;j++) l4[j] = l4[j]*al[j] + rs[j];
    #pragma unroll
    for (int fc=0;fc<4;fc++)
      #pragma unroll
      for (int j=0;j<4;j++){
        oacc[fc][j] *= al[j];
        Ps[(wave*16 + (lane>>4)*4 + j)*72 + fc*16 + (lane&15)] = f2bfr(sacc[fc][j]);
      }
    // O += P V   (Ps rows are wave-private: no barrier needed)
    #pragma unroll
    for (int ks=0; ks<2; ks++){
      bf16x8 ap = *(const bf16x8*)&Ps[(wave*16 + (lane&15))*72 + ks*32 + (lane>>4)*8];
      #pragma unroll
      for (int fc=0;fc<4;fc++){
        bf16x8 bv = *(const bf16x8*)&Vt[(fc*16 + (lane&15))*72 + ks*32 + (lane>>4)*8];
        oacc[fc] = __builtin_amdgcn_mfma_f32_16x16x32_bf16(ap, bv, oacc[fc], 0,0,0);
      }
    }
  }
  #pragma unroll
  for (int fc=0;fc<4;fc++)
    #pragma unroll
    for (int j=0;j<4;j++){
      int r = ql0 + wave*16 + (lane>>4)*4 + j;
      int c = h*E_ + fc*16 + (lane&15);
      o[((size_t)b*LSEQ_ + r)*D_ + c] = f2bfr(oacc[fc][j] / l4[j]);
    }
}

// ---------------- launcher ----------------
extern "C" void kernel_launch(void* const* d_in, const int* in_sizes, int n_in,
                              void* d_out, int out_size, void* d_ws, size_t ws_size,
                              hipStream_t stream){
  (void)in_sizes; (void)n_in; (void)out_size;
  const int*   tokens = (const int*)d_in[0];
  const float* tok_emb= (const float*)d_in[2];
  const float* pos_emb= (const float*)d_in[3];
  const float* Wq = (const float*)d_in[4];
  const float* bq = (const float*)d_in[5];
  const float* Wk = (const float*)d_in[6];
  const float* bk = (const float*)d_in[7];
  const float* Wv = (const float*)d_in[8];
  const float* bv = (const float*)d_in[9];
  const float* Wo = (const float*)d_in[10];
  const float* bo = (const float*)d_in[11];
  const float* W1 = (const float*)d_in[12];
  const float* b1 = (const float*)d_in[13];
  const float* W2 = (const float*)d_in[14];
  const float* b2 = (const float*)d_in[15];
  const float* ln1g = (const float*)d_in[16];
  const float* ln1b = (const float*)d_in[17];
  const float* ln3g = (const float*)d_in[18];
  const float* ln3b = (const float*)d_in[19];
  const float* lnfg = (const float*)d_in[20];
  const float* lnfb = (const float*)d_in[21];
  const float* Wout = (const float*)d_in[22];
  const float* bout = (const float*)d_in[23];

  char* p = (char*)d_ws;
  float* x             = (float*)p;           p += (size_t)M_*D_*sizeof(float);
  unsigned short* h    = (unsigned short*)p;  p += (size_t)M_*D_*2;
  unsigned short* qkv  = (unsigned short*)p;  p += (size_t)M_*QKVW*2;
  unsigned short* ob   = (unsigned short*)p;  p += (size_t)M_*D_*2;
  unsigned short* ffh  = (unsigned short*)p;  p += (size_t)M_*DF_*2;
  unsigned short* wt   = (unsigned short*)p;  p += (size_t)V_*D_*2;   // reusable WT buffer
  float* bqkv          = (float*)p;           p += (size_t)QKVW*sizeof(float);
  if ((size_t)(p - (char*)d_ws) > ws_size) return;   // insufficient workspace: fail cleanly

  embed_kernel<<<M_, 256, 0, stream>>>(tokens, tok_emb, pos_emb, x);
  for (int i=0;i<NL_;i++){
    const size_t wOff  = (size_t)i*D_*D_;
    const size_t w1Off = (size_t)i*D_*DF_;
    transpose_kernel<<<dim3(D_/64, D_/64), 256, 0, stream>>>(Wq + wOff, wt, D_, D_, 0);
    transpose_kernel<<<dim3(D_/64, D_/64), 256, 0, stream>>>(Wk + wOff, wt, D_, D_, D_);
    transpose_kernel<<<dim3(D_/64, D_/64), 256, 0, stream>>>(Wv + wOff, wt, D_, D_, 2*D_);
    concat_bias<<<QKVW/256, 256, 0, stream>>>(bq + i*D_, bk + i*D_, bv + i*D_, bqkv);
    ln_kernel<<<M_, 256, 0, stream>>>(x, ln1g + i*D_, ln1b + i*D_, h);
    gemm_bt<0><<<dim3(M_/128, QKVW/128), 256, 0, stream>>>(h, wt, bqkv, qkv, nullptr, D_, QKVW);
    attn_kernel<<<dim3(LSEQ_/64, B_*H_), 256, 0, stream>>>(qkv, ob);
    transpose_kernel<<<dim3(D_/64, D_/64), 256, 0, stream>>>(Wo + wOff, wt, D_, D_, 0);
    gemm_bt<2><<<dim3(M_/128, D_/128), 256, 0, stream>>>(ob, wt, bo + i*D_, nullptr, x, D_, D_);
    ln_kernel<<<M_, 256, 0, stream>>>(x, ln3g + i*D_, ln3b + i*D_, h);
    transpose_kernel<<<dim3(DF_/64, D_/64), 256, 0, stream>>>(W1 + w1Off, wt, DF_, D_, 0);
    gemm_bt<1><<<dim3(M_/128, DF_/128), 256, 0, stream>>>(h, wt, b1 + i*DF_, ffh, nullptr, D_, DF_);
    transpose_kernel<<<dim3(D_/64, DF_/64), 256, 0, stream>>>(W2 + w1Off, wt, D_, DF_, 0);
    gemm_bt<2><<<dim3(M_/128, D_/128), 256, 0, stream>>>(ffh, wt, b2 + i*D_, nullptr, x, DF_, D_);
  }
  ln_kernel<<<M_, 256, 0, stream>>>(x, lnfg, lnfb, h);
  transpose_kernel<<<dim3(V_/64, D_/64), 256, 0, stream>>>(Wout, wt, V_, D_, 0);
  gemm_bt<3><<<dim3(M_/128, V_/128), 256, 0, stream>>>(h, wt, bout, nullptr, (float*)d_out, D_, V_);
}